// Round 11
// baseline (157.752 us; speedup 1.0000x reference)
//
#include <hip/hip_runtime.h>
#include <hip/hip_bf16.h>

typedef __attribute__((ext_vector_type(8))) __bf16 bf16x8;
typedef __attribute__((ext_vector_type(4))) float f32x4;
typedef __attribute__((ext_vector_type(4))) int int4v;

#define NB 8
#define NN 2048
#define ND 256
#define L2E 1.44269504f
#define AS1 __attribute__((address_space(1)))
#define AS3 __attribute__((address_space(3)))

// ---------------------------------------------------------------------------
// KPREP: grid-partitioned fusion of three independent preps (one dispatch):
//   blocks [0,512):    k1 role  - hT2[b][jc][d][32] bf16 via MFMA
//   blocks [512,768):  k2 role  - elc/erx score tables
//   blocks [768,2816): k5 role  - adj -> bitmask (134 MB HBM stream)
// adj stream saturates HBM while k1's MFMA runs concurrently.
// ---------------------------------------------------------------------------
__global__ __launch_bounds__(256) void kprep(
    const float* __restrict__ x, const float* __restrict__ W,
    const float* __restrict__ a, const int* __restrict__ adj,
    __bf16* __restrict__ hT2, float* __restrict__ elc,
    float* __restrict__ erx, unsigned long long* __restrict__ mask) {
  __shared__ __bf16 hlds[256 * 34];
  __shared__ float wls[ND], wrs[ND];
  int blk = blockIdx.x;
  int tid = threadIdx.x;

  if (blk >= 768) {
    // ---- k5 role: pack adj into bitmask; pure linear stream ----
    const long NSEG = (long)NB * NN * (NN / 64);  // 524288
    int lane = tid & 63;
    long gw = ((long)(blk - 768) * 256 + tid) >> 6;
    long stride = (2048L * 256) >> 6;  // 8192 waves
    for (long s = gw; s < NSEG; s += stride) {
      int v = adj[s * 64 + lane];
      unsigned long long m = __ballot(v != 0);
      if (lane == 0) mask[s] = m;
    }
    return;
  }

  if (blk >= 512) {
    // ---- k2 role: elc[bn] = (-0.8*el-16)*log2e ; erx[bn] = (er-16)*log2e ----
    int t = tid;
    {
      float swl = 0.f, swr = 0.f;
#pragma unroll 8
      for (int o = 0; o < ND; ++o) {
        float wv = W[(long)o * ND + t];
        swl = fmaf(a[o], wv, swl);
        swr = fmaf(a[ND + o], wv, swr);
      }
      wls[t] = swl;
      wrs[t] = swr;
    }
    __syncthreads();
    int r = t >> 2, q = t & 3;
    long row = (long)(blk - 512) * 64 + r;
    const f32x4* xr = (const f32x4*)(x + row * ND);
    float sl = 0.f, sr = 0.f;
#pragma unroll
    for (int ii = 0; ii < 16; ++ii) {
      int idx = q + (ii << 2);
      f32x4 xv = xr[idx];
      f32x4 lv = *(const f32x4*)(wls + idx * 4);
      f32x4 rv = *(const f32x4*)(wrs + idx * 4);
      sl += xv[0] * lv[0] + xv[1] * lv[1] + xv[2] * lv[2] + xv[3] * lv[3];
      sr += xv[0] * rv[0] + xv[1] * rv[1] + xv[2] * rv[2] + xv[3] * rv[3];
    }
    sl += __shfl_xor(sl, 1);
    sl += __shfl_xor(sl, 2);
    sr += __shfl_xor(sr, 1);
    sr += __shfl_xor(sr, 2);
    if (q == 0) {
      elc[row] = (-0.8f * sl - 16.0f) * L2E;
      erx[row] = (sr - 16.0f) * L2E;
    }
    return;
  }

  // ---- k1 role: h = x @ W^T, store hT2 chunk-contiguous ----
  int wid = tid >> 6, lane = tid & 63;
  int msub = wid & 1, nh = wid >> 1;
  int lrow = lane & 15, kg = lane >> 4;
  int m0 = blk * 32;
  int row = m0 + msub * 16 + lrow;

  f32x4 acc[8];
#pragma unroll
  for (int f = 0; f < 8; ++f) acc[f] = (f32x4){0.f, 0.f, 0.f, 0.f};

#pragma unroll
  for (int k0 = 0; k0 < ND; k0 += 32) {
    int kk = k0 + kg * 8;
    const f32x4* xa = (const f32x4*)(x + (long)row * ND + kk);
    f32x4 a0 = xa[0], a1 = xa[1];
    bf16x8 afrag;
    afrag[0] = (__bf16)a0[0]; afrag[1] = (__bf16)a0[1];
    afrag[2] = (__bf16)a0[2]; afrag[3] = (__bf16)a0[3];
    afrag[4] = (__bf16)a1[0]; afrag[5] = (__bf16)a1[1];
    afrag[6] = (__bf16)a1[2]; afrag[7] = (__bf16)a1[3];
#pragma unroll
    for (int f = 0; f < 8; ++f) {
      int o = nh * 128 + f * 16 + lrow;
      const f32x4* wb = (const f32x4*)(W + (long)o * ND + kk);
      f32x4 b0 = wb[0], b1 = wb[1];
      bf16x8 bfrag;
      bfrag[0] = (__bf16)b0[0]; bfrag[1] = (__bf16)b0[1];
      bfrag[2] = (__bf16)b0[2]; bfrag[3] = (__bf16)b0[3];
      bfrag[4] = (__bf16)b1[0]; bfrag[5] = (__bf16)b1[1];
      bfrag[6] = (__bf16)b1[2]; bfrag[7] = (__bf16)b1[3];
      acc[f] = __builtin_amdgcn_mfma_f32_16x16x32_bf16(afrag, bfrag, acc[f], 0, 0, 0);
    }
  }

#pragma unroll
  for (int f = 0; f < 8; ++f) {
    int d = nh * 128 + f * 16 + lrow;
#pragma unroll
    for (int r = 0; r < 4; ++r) {
      int nloc = msub * 16 + kg * 4 + r;
      hlds[d * 34 + nloc] = (__bf16)acc[f][r];
    }
  }
  __syncthreads();
  {
    int b = m0 >> 11;
    int jc = (m0 & (NN - 1)) >> 5;
    const int* src = (const int*)(hlds + tid * 34);
    int tmp[16];
#pragma unroll
    for (int j = 0; j < 16; ++j) tmp[j] = src[j];
    __bf16* dst = hT2 + (((long)b * 64 + jc) * 256 + tid) * 32;
#pragma unroll
    for (int j = 0; j < 4; ++j)
      *(int4v*)(dst + j * 8) = *(int4v*)(tmp + j * 4);
  }
}

// ---------------------------------------------------------------------------
// K3: fused mask + softmax + PV (r8-proven structure + counted 2-phase slack).
// 512 thr = 8 waves (isub=w&1 rowgroup, dh=w>>1 64-d quarter). 32-j chunks;
// 4-buffer hT ring via global_load_lds (2 insts/thread/chunk, r6/r8 swizzle
// pair), steady vmcnt(4) (2 chunks in flight). Mask tile XOR-flat in LDS,
// erx in LDS (1 float/row). Main loop: ZERO global loads.
// p = bit ? exp2(max(x16, 0.2*x16 + 3.2*L2E + elc_i)) : 0.
// LDS = 64 + 8 + 8 = 80 KB exactly -> 2 blocks/CU.
// ---------------------------------------------------------------------------
__global__ __launch_bounds__(512, 4) void k3_main(
    const unsigned* __restrict__ mask32, const __bf16* __restrict__ hT2,
    const float* __restrict__ elc, const float* __restrict__ erx,
    float* __restrict__ out) {
  __shared__ __bf16 hbuf[4][8192];     // 64 KB
  __shared__ float er_lds[NN];         // 8 KB
  __shared__ unsigned mask_lds[2048];  // 8 KB flat [R*64 + (w ^ (R&31))]

  int blk = blockIdx.x;
  int b = blk & 7;    // batch -> XCD pin
  int it = blk >> 3;  // i-tile 0..63
  int tid = threadIdx.x;
  int wid = tid >> 6, lane = tid & 63;
  int isub = wid & 1, dh = wid >> 1;  // dh 0..3: 64-d quarter
  int lrow = lane & 15, kg = lane >> 4, kg8 = kg * 8;
  int irow = it * 32 + isub * 16 + lrow;

  const __bf16* hT2b = hT2 + (long)b * 64 * 8192;
  const unsigned* maskb = mask32 + ((long)b * NN + (long)it * 32) * 64;
  const float* erxb = erx + (long)b * NN;
  float c1s = elc[b * NN + irow];

  // prologue loads: er (1 gload_lds), hT chunks 0-2 (6), mask (1 reg int4)
  __builtin_amdgcn_global_load_lds((const AS1 void*)(erxb + tid * 4),
                                   (AS3 void*)(er_lds + tid * 4), 16, 0, 0);

  // stage addressing (r8-proven pair): unit idx = inst*512+tid ->
  // d = idx>>2, slot = idx&3, jlog = slot ^ ((d>>1)&3) (inst-invariant).
  int d0 = tid >> 2, slot = tid & 3;
  int jlog = slot ^ ((d0 >> 1) & 3);
  const __bf16* sgbase = hT2b + d0 * 32 + jlog * 8;

#define STAGEH(BI, TCV)                                                       \
  {                                                                           \
    const __bf16* s_ = sgbase + (long)(TCV)*8192;                             \
    __builtin_amdgcn_global_load_lds((const AS1 void*)(s_),                   \
                                     (AS3 void*)(&hbuf[BI][tid * 8]), 16, 0, 0); \
    __builtin_amdgcn_global_load_lds(                                         \
        (const AS1 void*)(s_ + 4096),                                         \
        (AS3 void*)(&hbuf[BI][4096 + tid * 8]), 16, 0, 0);                    \
  }

  STAGEH(0, 0);
  STAGEH(1, 1);
  STAGEH(2, 2);
  int4v mw = *(const int4v*)(maskb + tid * 4);

  asm volatile("s_waitcnt vmcnt(0)" ::: "memory");  // one-time full drain
  {
    int R = tid >> 4;
    int w0 = (tid & 15) * 4;
#pragma unroll
    for (int i = 0; i < 4; ++i)
      mask_lds[R * 64 + ((w0 + i) ^ (R & 31))] = (unsigned)mw[i];
  }
  asm volatile("s_waitcnt lgkmcnt(0)" ::: "memory");
  __builtin_amdgcn_s_barrier();

  // ds_read: byte = (dh*64 + f*16 + lrow)*64 + (kg^((lrow>>1)&3))*16
  int hoff = (dh * 64 + lrow) * 64 + (kg ^ ((lrow >> 1) & 3)) * 16;
  int d_base = dh * 64 + lrow;
  int mrow = isub * 16 + lrow;
  int mbase = mrow * 64;
  int mxor = mrow & 31;

  f32x4 acc[4];
#pragma unroll
  for (int f = 0; f < 4; ++f) acc[f] = (f32x4){0.f, 0.f, 0.f, 0.f};
  float den = 0.f;

#define COMPUTE(BI, TCV)                                                      \
  {                                                                           \
    unsigned msh = mask_lds[mbase + ((TCV) ^ mxor)] >> kg8;                   \
    const float* ep_ = er_lds + (TCV)*32 + kg8;                               \
    f32x4 xa_ = *(const f32x4*)ep_;                                           \
    f32x4 xb_ = *(const f32x4*)(ep_ + 4);                                     \
    bf16x8 pfrag;                                                             \
    float ps = 0.f;                                                           \
    _Pragma("unroll") for (int e = 0; e < 8; ++e) {                           \
      float x16 = (e < 4) ? xa_[e] : xb_[e - 4];                              \
      float x02 = fmaf(0.2f, x16, 4.61662413f);                               \
      float m_ = fmaxf(x16, x02 + c1s);                                       \
      float p = __builtin_amdgcn_exp2f(m_);                                   \
      p = ((msh >> e) & 1u) ? p : 0.0f;                                       \
      ps += p;                                                                \
      pfrag[e] = (__bf16)p;                                                   \
    }                                                                         \
    den += ps;                                                                \
    const char* hb_ = (const char*)&hbuf[BI][0];                              \
    __builtin_amdgcn_s_setprio(1);                                            \
    _Pragma("unroll") for (int f = 0; f < 4; ++f) {                           \
      bf16x8 bfr = *(const bf16x8*)(hb_ + hoff + f * 1024);                   \
      acc[f] = __builtin_amdgcn_mfma_f32_16x16x32_bf16(pfrag, bfr, acc[f], 0, 0, 0); \
    }                                                                         \
    __builtin_amdgcn_s_setprio(0);                                            \
  }

#define WAITB(VMN)                                       \
  asm volatile("s_waitcnt vmcnt(" VMN ")" ::: "memory"); \
  __builtin_amdgcn_s_barrier();

  // main: phases 0..59 (stages 3..62); steady-state 2 chunks in flight
  for (int T = 0; T < 15; ++T) {
    int tc = T * 4;
    WAITB("4"); STAGEH(3, tc + 3); COMPUTE(0, tc);
    WAITB("4"); STAGEH(0, tc + 4); COMPUTE(1, tc + 1);
    WAITB("4"); STAGEH(1, tc + 5); COMPUTE(2, tc + 2);
    WAITB("4"); STAGEH(2, tc + 6); COMPUTE(3, tc + 3);
  }
  // tail: 60..63 (stage 63 only)
  WAITB("4"); STAGEH(3, 63); COMPUTE(0, 60);
  WAITB("4"); COMPUTE(1, 61);
  WAITB("2"); COMPUTE(2, 62);
  WAITB("0"); COMPUTE(3, 63);

#undef STAGEH
#undef COMPUTE
#undef WAITB

  // den: sum across the 4 k-groups (lanes with same l&15)
  den += __shfl_xor(den, 16);
  den += __shfl_xor(den, 32);
  float rdiv[4];
#pragma unroll
  for (int r = 0; r < 4; ++r) rdiv[r] = 1.0f / __shfl(den, kg * 4 + r);

  float* outb = out + ((long)b * NN + it * 32 + isub * 16) * ND;
#pragma unroll
  for (int f = 0; f < 4; ++f) {
    int dcol = d_base + f * 16;
#pragma unroll
    for (int r = 0; r < 4; ++r)
      outb[(long)(kg * 4 + r) * ND + dcol] = acc[f][r] * rdiv[r];
  }
}

// ---------------------------------------------------------------------------
extern "C" void kernel_launch(void* const* d_in, const int* in_sizes, int n_in,
                              void* d_out, int out_size, void* d_ws,
                              size_t ws_size, hipStream_t stream) {
  const float* x = (const float*)d_in[0];
  const int* adj = (const int*)d_in[1];
  const float* W = (const float*)d_in[2];
  const float* a = (const float*)d_in[3];
  float* out = (float*)d_out;

  char* ws = (char*)d_ws;
  const size_t base = 8u * 1024u * 1024u;
  __bf16* hT2 = (__bf16*)ws;                  // 8 MB
  float* elc = (float*)(ws + base);           // 64 KB
  float* erx = (float*)(ws + base + 65536u);  // 64 KB
  unsigned long long* mask =
      (unsigned long long*)(ws + base + 131072u);  // 4 MB

  kprep<<<dim3(2816), dim3(256), 0, stream>>>(x, W, a, adj, hT2, elc, erx,
                                              mask);
  k3_main<<<dim3(512), dim3(512), 0, stream>>>((const unsigned*)mask, hT2, elc,
                                               erx, out);
}

// Round 12
// 124.904 us; speedup vs baseline: 1.2630x; 1.2630x over previous
//
#include <hip/hip_runtime.h>
#include <hip/hip_bf16.h>

typedef __attribute__((ext_vector_type(8))) __bf16 bf16x8;
typedef __attribute__((ext_vector_type(4))) float f32x4;
typedef __attribute__((ext_vector_type(4))) int int4v;

#define NB 8
#define NN 2048
#define ND 256
#define L2E 1.44269504f
#define AS1 __attribute__((address_space(1)))
#define AS3 __attribute__((address_space(3)))

// ---------------------------------------------------------------------------
// K5B: adj -> bitmask, ILP version (no ballot, no cross-lane). Thread g packs
// adj[g*32 .. g*32+31] into mask32[g] via 8 independent int4 loads (8 KB in
// flight per wave). 4096 blocks x 256 thr; pure BW stream.
// mask32[(b*NN+row)*64 + w] bit q = adj[b][row][w*32+q] != 0.
// ---------------------------------------------------------------------------
__global__ __launch_bounds__(256) void k5b_pack(
    const int* __restrict__ adj, unsigned* __restrict__ mask32) {
  long g = (long)blockIdx.x * 256 + threadIdx.x;  // word index < 1048576
  const int4v* ap = (const int4v*)(adj + g * 32);
  int4v v0 = ap[0], v1 = ap[1], v2 = ap[2], v3 = ap[3];
  int4v v4 = ap[4], v5 = ap[5], v6 = ap[6], v7 = ap[7];
  unsigned m = 0;
#define PK(VV, BASE)                                                   \
  _Pragma("unroll") for (int k = 0; k < 4; ++k)                        \
      m |= (VV[k] != 0 ? 1u : 0u) << ((BASE) + k);
  PK(v0, 0) PK(v1, 4) PK(v2, 8) PK(v3, 12)
  PK(v4, 16) PK(v5, 20) PK(v6, 24) PK(v7, 28)
#undef PK
  mask32[g] = m;
}

// ---------------------------------------------------------------------------
// K2: per block recompute wl/wr = W^T a halves (L2-hot W), then row dots.
//   elc[bn] = (-0.8*el - 16) * log2e
//   erx[bn] = (er - 16) * log2e     (x02 = 0.2*x16 + 3.2*L2E in k3)
// ---------------------------------------------------------------------------
__global__ __launch_bounds__(256) void k2_elr(
    const float* __restrict__ x, const float* __restrict__ W,
    const float* __restrict__ a, float* __restrict__ elc,
    float* __restrict__ erx) {
  __shared__ float wls[ND], wrs[ND];
  int t = threadIdx.x;
  {
    float swl = 0.f, swr = 0.f;
#pragma unroll 8
    for (int o = 0; o < ND; ++o) {
      float wv = W[(long)o * ND + t];
      swl = fmaf(a[o], wv, swl);
      swr = fmaf(a[ND + o], wv, swr);
    }
    wls[t] = swl;
    wrs[t] = swr;
  }
  __syncthreads();
  int r = t >> 2, q = t & 3;
  long row = (long)blockIdx.x * 64 + r;
  const f32x4* xr = (const f32x4*)(x + row * ND);
  float sl = 0.f, sr = 0.f;
#pragma unroll
  for (int ii = 0; ii < 16; ++ii) {
    int idx = q + (ii << 2);
    f32x4 xv = xr[idx];
    f32x4 lv = *(const f32x4*)(wls + idx * 4);
    f32x4 rv = *(const f32x4*)(wrs + idx * 4);
    sl += xv[0] * lv[0] + xv[1] * lv[1] + xv[2] * lv[2] + xv[3] * lv[3];
    sr += xv[0] * rv[0] + xv[1] * rv[1] + xv[2] * rv[2] + xv[3] * rv[3];
  }
  sl += __shfl_xor(sl, 1);
  sl += __shfl_xor(sl, 2);
  sr += __shfl_xor(sr, 1);
  sr += __shfl_xor(sr, 2);
  if (q == 0) {
    elc[row] = (-0.8f * sl - 16.0f) * L2E;
    erx[row] = (sr - 16.0f) * L2E;
  }
}

// ---------------------------------------------------------------------------
// K1: h = x @ W^T via bf16 MFMA; write hT2[b][jc][d][32] bf16 (chunk-
// contiguous: one 32-j chunk x 256 d = 16 KB sequential block).
// ---------------------------------------------------------------------------
__global__ __launch_bounds__(256) void k1_h(
    const float* __restrict__ x, const float* __restrict__ W,
    __bf16* __restrict__ hT2) {
  __shared__ __bf16 hlds[256 * 34];
  int tid = threadIdx.x;
  int wid = tid >> 6, lane = tid & 63;
  int msub = wid & 1, nh = wid >> 1;
  int lrow = lane & 15, kg = lane >> 4;
  int m0 = blockIdx.x * 32;
  int row = m0 + msub * 16 + lrow;

  f32x4 acc[8];
#pragma unroll
  for (int f = 0; f < 8; ++f) acc[f] = (f32x4){0.f, 0.f, 0.f, 0.f};

#pragma unroll
  for (int k0 = 0; k0 < ND; k0 += 32) {
    int kk = k0 + kg * 8;
    const f32x4* xa = (const f32x4*)(x + (long)row * ND + kk);
    f32x4 a0 = xa[0], a1 = xa[1];
    bf16x8 afrag;
    afrag[0] = (__bf16)a0[0]; afrag[1] = (__bf16)a0[1];
    afrag[2] = (__bf16)a0[2]; afrag[3] = (__bf16)a0[3];
    afrag[4] = (__bf16)a1[0]; afrag[5] = (__bf16)a1[1];
    afrag[6] = (__bf16)a1[2]; afrag[7] = (__bf16)a1[3];
#pragma unroll
    for (int f = 0; f < 8; ++f) {
      int o = nh * 128 + f * 16 + lrow;
      const f32x4* wb = (const f32x4*)(W + (long)o * ND + kk);
      f32x4 b0 = wb[0], b1 = wb[1];
      bf16x8 bfrag;
      bfrag[0] = (__bf16)b0[0]; bfrag[1] = (__bf16)b0[1];
      bfrag[2] = (__bf16)b0[2]; bfrag[3] = (__bf16)b0[3];
      bfrag[4] = (__bf16)b1[0]; bfrag[5] = (__bf16)b1[1];
      bfrag[6] = (__bf16)b1[2]; bfrag[7] = (__bf16)b1[3];
      acc[f] = __builtin_amdgcn_mfma_f32_16x16x32_bf16(afrag, bfrag, acc[f], 0, 0, 0);
    }
  }

#pragma unroll
  for (int f = 0; f < 8; ++f) {
    int d = nh * 128 + f * 16 + lrow;
#pragma unroll
    for (int r = 0; r < 4; ++r) {
      int nloc = msub * 16 + kg * 4 + r;
      hlds[d * 34 + nloc] = (__bf16)acc[f][r];
    }
  }
  __syncthreads();
  {
    int b = m0 >> 11;
    int jc = (m0 & (NN - 1)) >> 5;
    const int* src = (const int*)(hlds + tid * 34);
    int tmp[16];
#pragma unroll
    for (int j = 0; j < 16; ++j) tmp[j] = src[j];
    __bf16* dst = hT2 + (((long)b * 64 + jc) * 256 + tid) * 32;
#pragma unroll
    for (int j = 0; j < 4; ++j)
      *(int4v*)(dst + j * 8) = *(int4v*)(tmp + j * 4);
  }
}

// ---------------------------------------------------------------------------
// K3: fused mask + softmax + PV (r11 structure, unchanged). 512 thr = 8 waves
// (isub=w&1 rowgroup, dh=w>>1 64-d quarter). 32-j chunks; 4-buffer hT ring
// via global_load_lds (2 insts/thread/chunk, proven swizzle pair), steady
// vmcnt(4). Mask tile XOR-flat in LDS, erx in LDS. Main loop: zero global
// loads. p = bit ? exp2(max(x16, 0.2*x16 + 3.2*L2E + elc_i)) : 0.
// LDS = 64 + 8 + 8 = 80 KB -> 2 blocks/CU.
// ---------------------------------------------------------------------------
__global__ __launch_bounds__(512, 4) void k3_main(
    const unsigned* __restrict__ mask32, const __bf16* __restrict__ hT2,
    const float* __restrict__ elc, const float* __restrict__ erx,
    float* __restrict__ out) {
  __shared__ __bf16 hbuf[4][8192];     // 64 KB
  __shared__ float er_lds[NN];         // 8 KB
  __shared__ unsigned mask_lds[2048];  // 8 KB flat [R*64 + (w ^ (R&31))]

  int blk = blockIdx.x;
  int b = blk & 7;    // batch -> XCD pin
  int it = blk >> 3;  // i-tile 0..63
  int tid = threadIdx.x;
  int wid = tid >> 6, lane = tid & 63;
  int isub = wid & 1, dh = wid >> 1;  // dh 0..3: 64-d quarter
  int lrow = lane & 15, kg = lane >> 4, kg8 = kg * 8;
  int irow = it * 32 + isub * 16 + lrow;

  const __bf16* hT2b = hT2 + (long)b * 64 * 8192;
  const unsigned* maskb = mask32 + ((long)b * NN + (long)it * 32) * 64;
  const float* erxb = erx + (long)b * NN;
  float c1s = elc[b * NN + irow];

  __builtin_amdgcn_global_load_lds((const AS1 void*)(erxb + tid * 4),
                                   (AS3 void*)(er_lds + tid * 4), 16, 0, 0);

  int d0 = tid >> 2, slot = tid & 3;
  int jlog = slot ^ ((d0 >> 1) & 3);
  const __bf16* sgbase = hT2b + d0 * 32 + jlog * 8;

#define STAGEH(BI, TCV)                                                       \
  {                                                                           \
    const __bf16* s_ = sgbase + (long)(TCV)*8192;                             \
    __builtin_amdgcn_global_load_lds((const AS1 void*)(s_),                   \
                                     (AS3 void*)(&hbuf[BI][tid * 8]), 16, 0, 0); \
    __builtin_amdgcn_global_load_lds(                                         \
        (const AS1 void*)(s_ + 4096),                                         \
        (AS3 void*)(&hbuf[BI][4096 + tid * 8]), 16, 0, 0);                    \
  }

  STAGEH(0, 0);
  STAGEH(1, 1);
  STAGEH(2, 2);
  int4v mw = *(const int4v*)(maskb + tid * 4);

  asm volatile("s_waitcnt vmcnt(0)" ::: "memory");  // one-time full drain
  {
    int R = tid >> 4;
    int w0 = (tid & 15) * 4;
#pragma unroll
    for (int i = 0; i < 4; ++i)
      mask_lds[R * 64 + ((w0 + i) ^ (R & 31))] = (unsigned)mw[i];
  }
  asm volatile("s_waitcnt lgkmcnt(0)" ::: "memory");
  __builtin_amdgcn_s_barrier();

  int hoff = (dh * 64 + lrow) * 64 + (kg ^ ((lrow >> 1) & 3)) * 16;
  int d_base = dh * 64 + lrow;
  int mrow = isub * 16 + lrow;
  int mbase = mrow * 64;
  int mxor = mrow & 31;

  f32x4 acc[4];
#pragma unroll
  for (int f = 0; f < 4; ++f) acc[f] = (f32x4){0.f, 0.f, 0.f, 0.f};
  float den = 0.f;

#define COMPUTE(BI, TCV)                                                      \
  {                                                                           \
    unsigned msh = mask_lds[mbase + ((TCV) ^ mxor)] >> kg8;                   \
    const float* ep_ = er_lds + (TCV)*32 + kg8;                               \
    f32x4 xa_ = *(const f32x4*)ep_;                                           \
    f32x4 xb_ = *(const f32x4*)(ep_ + 4);                                     \
    bf16x8 pfrag;                                                             \
    float ps = 0.f;                                                           \
    _Pragma("unroll") for (int e = 0; e < 8; ++e) {                           \
      float x16 = (e < 4) ? xa_[e] : xb_[e - 4];                              \
      float x02 = fmaf(0.2f, x16, 4.61662413f);                               \
      float m_ = fmaxf(x16, x02 + c1s);                                       \
      float p = __builtin_amdgcn_exp2f(m_);                                   \
      p = ((msh >> e) & 1u) ? p : 0.0f;                                       \
      ps += p;                                                                \
      pfrag[e] = (__bf16)p;                                                   \
    }                                                                         \
    den += ps;                                                                \
    const char* hb_ = (const char*)&hbuf[BI][0];                              \
    __builtin_amdgcn_s_setprio(1);                                            \
    _Pragma("unroll") for (int f = 0; f < 4; ++f) {                           \
      bf16x8 bfr = *(const bf16x8*)(hb_ + hoff + f * 1024);                   \
      acc[f] = __builtin_amdgcn_mfma_f32_16x16x32_bf16(pfrag, bfr, acc[f], 0, 0, 0); \
    }                                                                         \
    __builtin_amdgcn_s_setprio(0);                                            \
  }

#define WAITB(VMN)                                       \
  asm volatile("s_waitcnt vmcnt(" VMN ")" ::: "memory"); \
  __builtin_amdgcn_s_barrier();

  for (int T = 0; T < 15; ++T) {
    int tc = T * 4;
    WAITB("4"); STAGEH(3, tc + 3); COMPUTE(0, tc);
    WAITB("4"); STAGEH(0, tc + 4); COMPUTE(1, tc + 1);
    WAITB("4"); STAGEH(1, tc + 5); COMPUTE(2, tc + 2);
    WAITB("4"); STAGEH(2, tc + 6); COMPUTE(3, tc + 3);
  }
  WAITB("4"); STAGEH(3, 63); COMPUTE(0, 60);
  WAITB("4"); COMPUTE(1, 61);
  WAITB("2"); COMPUTE(2, 62);
  WAITB("0"); COMPUTE(3, 63);

#undef STAGEH
#undef COMPUTE
#undef WAITB

  den += __shfl_xor(den, 16);
  den += __shfl_xor(den, 32);
  float rdiv[4];
#pragma unroll
  for (int r = 0; r < 4; ++r) rdiv[r] = 1.0f / __shfl(den, kg * 4 + r);

  float* outb = out + ((long)b * NN + it * 32 + isub * 16) * ND;
#pragma unroll
  for (int f = 0; f < 4; ++f) {
    int dcol = d_base + f * 16;
#pragma unroll
    for (int r = 0; r < 4; ++r)
      outb[(long)(kg * 4 + r) * ND + dcol] = acc[f][r] * rdiv[r];
  }
}

// ---------------------------------------------------------------------------
extern "C" void kernel_launch(void* const* d_in, const int* in_sizes, int n_in,
                              void* d_out, int out_size, void* d_ws,
                              size_t ws_size, hipStream_t stream) {
  const float* x = (const float*)d_in[0];
  const int* adj = (const int*)d_in[1];
  const float* W = (const float*)d_in[2];
  const float* a = (const float*)d_in[3];
  float* out = (float*)d_out;

  char* ws = (char*)d_ws;
  const size_t base = 8u * 1024u * 1024u;
  __bf16* hT2 = (__bf16*)ws;                  // 8 MB
  float* elc = (float*)(ws + base);           // 64 KB
  float* erx = (float*)(ws + base + 65536u);  // 64 KB
  unsigned* mask = (unsigned*)(ws + base + 131072u);  // 4 MB

  k5b_pack<<<dim3(4096), dim3(256), 0, stream>>>(adj, mask);
  k1_h<<<dim3(512), dim3(256), 0, stream>>>(x, W, hT2);
  k2_elr<<<dim3(256), dim3(256), 0, stream>>>(x, W, a, elc, erx);
  k3_main<<<dim3(512), dim3(512), 0, stream>>>(mask, hT2, elc, erx, out);
}